// Round 5
// baseline (829.977 us; speedup 1.0000x reference)
//
#include <hip/hip_runtime.h>
#include <hip/hip_bf16.h>
#include <math.h>

// Problem constants (reference: B,S,H,NH,HD = 2,2048,4096,32,128)
constexpr int Bc  = 2;
constexpr int Sc  = 2048;
constexpr int Hc  = 4096;
constexpr int NHc = 32;
constexpr int HDc = 128;

typedef __attribute__((ext_vector_type(8))) __bf16 bf16x8;
typedef __attribute__((ext_vector_type(4))) __bf16 bf16x4;
typedef __attribute__((ext_vector_type(4))) float  f32x4;

#if defined(__has_builtin)
#if __has_builtin(__builtin_amdgcn_global_load_lds)
#define HAS_GLL 1
#endif
#endif
#ifndef HAS_GLL
#define HAS_GLL 0
#endif

// raw v_exp_f32 (base-2). libm exp2f carries OCML edge handling (the round-3
// attn regression); the builtin is a single instruction.
__device__ __forceinline__ float fast_exp2(float x) {
#if defined(__has_builtin)
#if __has_builtin(__builtin_amdgcn_exp2f)
    return __builtin_amdgcn_exp2f(x);
#else
    return exp2f(x);
#endif
#else
    return exp2f(x);
#endif
}

// compiler fence (no instructions) + raw barrier: syncthreads WITHOUT the
// vmcnt(0) drain (that drain is the m97-structure stall).
#define CFENCE asm volatile("" ::: "memory")
#define BARRIER do { CFENCE; __builtin_amdgcn_s_barrier(); CFENCE; } while (0)
#define WAITVM(n) asm volatile("s_waitcnt vmcnt(" #n ")" ::: "memory")

// async global->LDS, 16B per lane. lds base must be wave-uniform; HW adds lane*16.
__device__ __forceinline__ void gll16(const __bf16* g, __bf16* lds_base, int lane) {
#if HAS_GLL
    __builtin_amdgcn_global_load_lds((const __attribute__((address_space(1))) void*)g,
                                     (__attribute__((address_space(3))) void*)lds_base,
                                     16, 0, 0);
#else
    *(int4*)(lds_base + lane * 8) = *(const int4*)g;
#endif
}

// ---------------------------------------------------------------------------
// fp32 -> bf16 conversion
// ---------------------------------------------------------------------------
__global__ void cvt_f32_bf16(const float* __restrict__ in, __bf16* __restrict__ out, int n) {
    int i = (blockIdx.x * blockDim.x + threadIdx.x) * 4;
    if (i >= n) return;
    const float4 v = *(const float4*)(in + i);
    bf16x4 o;
    o[0] = (__bf16)v.x; o[1] = (__bf16)v.y; o[2] = (__bf16)v.z; o[3] = (__bf16)v.w;
    *(bf16x4*)(out + i) = o;
}

// Build fused KV weight: rows 0..127 = Wk, rows 128..255 = Wv  (256 x 4096)
__global__ void build_wkv(const float* __restrict__ Wk, const float* __restrict__ Wv,
                          __bf16* __restrict__ out) {
    int i = (blockIdx.x * blockDim.x + threadIdx.x) * 4;
    if (i >= 256 * Hc) return;
    int row = i >> 12;
    int col = i & (Hc - 1);
    const float* src = (row < HDc) ? (Wk + (long)row * Hc + col)
                                   : (Wv + (long)(row - HDc) * Hc + col);
    const float4 v = *(const float4*)src;
    bf16x4 o;
    o[0] = (__bf16)v.x; o[1] = (__bf16)v.y; o[2] = (__bf16)v.z; o[3] = (__bf16)v.w;
    *(bf16x4*)(out + i) = o;
}

// ---------------------------------------------------------------------------
// NT GEMM "gemm256": 256x256 tile, BK=64, 512 thr (8 waves, 2Mx4N of 128x64),
// 8-phase-per-2-K-tiles schedule with counted vmcnt. Measured: ~1.5 PF, correct.
// ---------------------------------------------------------------------------
template <typename OUT>
__global__ __launch_bounds__(512, 2)
void gemm256(const __bf16* __restrict__ A, const __bf16* __restrict__ B,
             OUT* __restrict__ C, int M, int N, int K) {
    __shared__ __bf16 As[2][256 * 64];
    __shared__ __bf16 Bs[2][256 * 64];

    const int tid  = threadIdx.x;
    const int wave = tid >> 6, lane = tid & 63;
    const int lrow = lane & 15, quad = lane >> 4;
    const int wm = wave >> 2, wn = wave & 3;

    // XCD-aware bijective chunked swizzle (nwg = 256, %8 == 0)
    const int nwg = gridDim.x * gridDim.y;
    const int bid = blockIdx.y * gridDim.x + blockIdx.x;
    const int wg  = (bid & 7) * (nwg >> 3) + (bid >> 3);
    const int m0  = (wg / gridDim.x) * 256;
    const int n0  = (wg % gridDim.x) * 256;

    f32x4 acc[8][4] = {};

    // staging precompute: 2 chunks (1KB = 8 rows) per thread per group,
    // chunk id c = wave*2+it. Source col inverse-swizzled so LDS is linear.
    int srow[4][2], sbase[4][2];
    const int rp   = lane >> 3;                 // row within 8-row chunk
    const int scol = ((lane & 7) ^ rp) << 3;    // logical elem col
#pragma unroll
    for (int it = 0; it < 2; ++it) {
        const int c   = wave * 2 + it;
        const int rb0 = (c < 8) ? c * 8 : 128 + (c - 8) * 8;  // A qi0: [0,64)+[128,192)
        const int rb1 = (c >> 2) * 64 + (c & 3) * 8;          // B qj0: 4x 32-row slabs
        srow[0][it] = rb0 + rp;       sbase[0][it] = rb0 * 64;
        srow[1][it] = rb1 + rp;       sbase[1][it] = rb1 * 64;
        srow[2][it] = rb1 + 32 + rp;  sbase[2][it] = (rb1 + 32) * 64;
        srow[3][it] = rb0 + 64 + rp;  sbase[3][it] = (rb0 + 64) * 64;
    }
    const __bf16* Ab = A + (long)m0 * K;
    const __bf16* Bb = B + (long)n0 * K;

    auto stageg = [&](int g, int bu, long k0) {
        const __bf16* gb = (g == 0 || g == 3) ? Ab : Bb;
        __bf16* lb = (g == 0 || g == 3) ? &As[bu][0] : &Bs[bu][0];
#pragma unroll
        for (int it = 0; it < 2; ++it)
            gll16(gb + (long)srow[g][it] * K + k0 + scol, lb + sbase[g][it], lane);
    };

    const int fc0  = ((quad ^ (lrow & 7)) << 3);        // phys col, k-half 0
    const int fc1  = (((4 | quad) ^ (lrow & 7)) << 3);  // phys col, k-half 1
    const int arow = wm * 128 + lrow;                   // + qi*64 + i2*16
    const int brow = wn * 64 + lrow;                    // + qj*32 + j2*16

    const int nk = K >> 6;
    // prologue: stage tile 0 -> buf 0
    stageg(0, 0, 0); stageg(1, 0, 0); stageg(2, 0, 0); stageg(3, 0, 0);
    WAITVM(4);
    BARRIER;

    for (int kt = 0; kt < nk; ++kt) {
        const int bu = kt & 1;
        const bool more = (kt + 1 < nk);
        const long k1 = (long)(kt + 1) * 64;
        bf16x8 af[2][4], bv0[2][2], bv1[2][2];

        // ---- phase 0: read af(qi=0)+bv0(qj=0); stage g0(kt+1); MFMA (0,0)
#pragma unroll
        for (int i2 = 0; i2 < 4; ++i2) {
            af[0][i2] = *(const bf16x8*)&As[bu][(arow + i2 * 16) * 64 + fc0];
            af[1][i2] = *(const bf16x8*)&As[bu][(arow + i2 * 16) * 64 + fc1];
        }
#pragma unroll
        for (int j2 = 0; j2 < 2; ++j2) {
            bv0[0][j2] = *(const bf16x8*)&Bs[bu][(brow + j2 * 16) * 64 + fc0];
            bv0[1][j2] = *(const bf16x8*)&Bs[bu][(brow + j2 * 16) * 64 + fc1];
        }
        if (more) { stageg(0, bu ^ 1, k1); WAITVM(4); } else { WAITVM(0); }
        BARRIER;
        __builtin_amdgcn_s_setprio(1);
#pragma unroll
        for (int c = 0; c < 2; ++c)
#pragma unroll
            for (int i2 = 0; i2 < 4; ++i2)
#pragma unroll
                for (int j2 = 0; j2 < 2; ++j2)
                    acc[i2][j2] = __builtin_amdgcn_mfma_f32_16x16x32_bf16(
                        af[c][i2], bv0[c][j2], acc[i2][j2], 0, 0, 0);
        __builtin_amdgcn_s_setprio(0);
        BARRIER;

        // ---- phase 1: read bv1(qj=1); stage g1(kt+1); MFMA (0,1)
#pragma unroll
        for (int j2 = 0; j2 < 2; ++j2) {
            bv1[0][j2] = *(const bf16x8*)&Bs[bu][(brow + 32 + j2 * 16) * 64 + fc0];
            bv1[1][j2] = *(const bf16x8*)&Bs[bu][(brow + 32 + j2 * 16) * 64 + fc1];
        }
        if (more) { stageg(1, bu ^ 1, k1); WAITVM(4); } else { WAITVM(0); }
        BARRIER;
        __builtin_amdgcn_s_setprio(1);
#pragma unroll
        for (int c = 0; c < 2; ++c)
#pragma unroll
            for (int i2 = 0; i2 < 4; ++i2)
#pragma unroll
                for (int j2 = 0; j2 < 2; ++j2)
                    acc[i2][2 + j2] = __builtin_amdgcn_mfma_f32_16x16x32_bf16(
                        af[c][i2], bv1[c][j2], acc[i2][2 + j2], 0, 0, 0);
        __builtin_amdgcn_s_setprio(0);
        BARRIER;

        // ---- phase 2: read af(qi=1); stage g2(kt+1); MFMA (1,0)
#pragma unroll
        for (int i2 = 0; i2 < 4; ++i2) {
            af[0][i2] = *(const bf16x8*)&As[bu][(arow + 64 + i2 * 16) * 64 + fc0];
            af[1][i2] = *(const bf16x8*)&As[bu][(arow + 64 + i2 * 16) * 64 + fc1];
        }
        if (more) { stageg(2, bu ^ 1, k1); WAITVM(4); } else { WAITVM(0); }
        BARRIER;
        __builtin_amdgcn_s_setprio(1);
#pragma unroll
        for (int c = 0; c < 2; ++c)
#pragma unroll
            for (int i2 = 0; i2 < 4; ++i2)
#pragma unroll
                for (int j2 = 0; j2 < 2; ++j2)
                    acc[4 + i2][j2] = __builtin_amdgcn_mfma_f32_16x16x32_bf16(
                        af[c][i2], bv0[c][j2], acc[4 + i2][j2], 0, 0, 0);
        __builtin_amdgcn_s_setprio(0);
        BARRIER;

        // ---- phase 3: no reads; stage g3(kt+1); MFMA (1,1)
        if (more) { stageg(3, bu ^ 1, k1); WAITVM(4); } else { WAITVM(0); }
        BARRIER;
        __builtin_amdgcn_s_setprio(1);
#pragma unroll
        for (int c = 0; c < 2; ++c)
#pragma unroll
            for (int i2 = 0; i2 < 4; ++i2)
#pragma unroll
                for (int j2 = 0; j2 < 2; ++j2)
                    acc[4 + i2][2 + j2] = __builtin_amdgcn_mfma_f32_16x16x32_bf16(
                        af[c][i2], bv1[c][j2], acc[4 + i2][2 + j2], 0, 0, 0);
        __builtin_amdgcn_s_setprio(0);
        BARRIER;
    }

#pragma unroll
    for (int i = 0; i < 8; ++i) {
        const int row = m0 + wm * 128 + i * 16 + quad * 4;
#pragma unroll
        for (int j = 0; j < 4; ++j) {
            const int col = n0 + wn * 64 + j * 16 + lrow;
            OUT* cp = C + (long)row * N + col;
#pragma unroll
            for (int r = 0; r < 4; ++r) cp[(long)r * N] = (OUT)acc[i][j][r];
        }
    }
}

// 64x64-tile KV GEMM, now DOUBLE-BUFFERED (was single: full HBM latency
// exposed per K-iter x64 at 1 block/CU). Prefetch kt+1 right after the
// barrier, compute from buffer kt&1 (round-0 attn pattern).
template <typename OUT>
__global__ __launch_bounds__(256)
void gemm_bt64(const __bf16* __restrict__ A, const __bf16* __restrict__ B,
               OUT* __restrict__ C, int M, int N, int K) {
    __shared__ __bf16 As[2][64][64];
    __shared__ __bf16 Bs[2][64][64];

    const int tid  = threadIdx.x;
    const int wave = tid >> 6, lane = tid & 63;
    const int lrow = lane & 15, quad = lane >> 4;
    const int m0   = blockIdx.y * 64;
    const int n0   = blockIdx.x * 64;
    const int wr   = (wave >> 1) * 32;
    const int wc   = (wave & 1) * 32;

    f32x4 acc[2][2] = {};

    int srow[2], scol[2];
#pragma unroll
    for (int it = 0; it < 2; ++it) {
        int e = (wave * 2 + it) * 1024 + lane * 16;
        int r = e >> 7;
        int cb = (e >> 4) & 7;
        srow[it] = r;
        scol[it] = ((cb ^ (r & 7)) * 8);
    }
    const __bf16* Ab = A + (long)m0 * K;
    const __bf16* Bb = B + (long)n0 * K;

    auto stage = [&](int kt, int bu) {
        const long k0 = (long)kt * 64;
#pragma unroll
        for (int it = 0; it < 2; ++it)
            gll16(Ab + (long)srow[it] * K + k0 + scol[it], &As[bu][0][0] + (wave * 2 + it) * 512, lane);
#pragma unroll
        for (int it = 0; it < 2; ++it)
            gll16(Bb + (long)srow[it] * K + k0 + scol[it], &Bs[bu][0][0] + (wave * 2 + it) * 512, lane);
    };

    const int fcol0 = ((quad ^ (lrow & 7)) << 3);
    const int fcol1 = (((4 | quad) ^ (lrow & 7)) << 3);

    const int nk = K >> 6;
    stage(0, 0);
    for (int kt = 0; kt < nk; ++kt) {
        __syncthreads();                          // drains vmcnt -> tile kt ready
        if (kt + 1 < nk) stage(kt + 1, (kt + 1) & 1);
        const int bu = kt & 1;

#pragma unroll
        for (int c = 0; c < 2; ++c) {
            const int fc = c ? fcol1 : fcol0;
            bf16x8 af[2], bfv[2];
#pragma unroll
            for (int i = 0; i < 2; ++i) af[i]  = *(const bf16x8*)&As[bu][wr + i * 16 + lrow][fc];
#pragma unroll
            for (int j = 0; j < 2; ++j) bfv[j] = *(const bf16x8*)&Bs[bu][wc + j * 16 + lrow][fc];
#pragma unroll
            for (int i = 0; i < 2; ++i)
#pragma unroll
                for (int j = 0; j < 2; ++j)
                    acc[i][j] = __builtin_amdgcn_mfma_f32_16x16x32_bf16(af[i], bfv[j], acc[i][j], 0, 0, 0);
        }
    }

#pragma unroll
    for (int i = 0; i < 2; ++i) {
        const int row = m0 + wr + i * 16 + quad * 4;
#pragma unroll
        for (int j = 0; j < 2; ++j) {
            const int col = n0 + wc + j * 16 + lrow;
            OUT* cp = C + (long)row * N + col;
#pragma unroll
            for (int r = 0; r < 4; ++r) cp[(long)r * N] = (OUT)acc[i][j][r];
        }
    }
}

__global__ void rope_k(__bf16* __restrict__ KV, const float* __restrict__ cosb,
                       const float* __restrict__ sinb) {
    int gid  = blockIdx.x * blockDim.x + threadIdx.x;
    int row  = gid >> 3;
    int dblk = (gid & 7) * 8;
    int s    = row & (Sc - 1);
    __bf16* p = KV + (long)row * 256;
    const float* cp = cosb + s * HDc;
    const float* sp = sinb + s * HDc;
    bf16x8 lo = *(bf16x8*)(p + dblk);
    bf16x8 hi = *(bf16x8*)(p + dblk + 64);
    bf16x8 olo, ohi;
#pragma unroll
    for (int j = 0; j < 8; ++j) {
        float ql = (float)lo[j], qh = (float)hi[j];
        float cl = cp[dblk + j],      sl = sp[dblk + j];
        float ch = cp[dblk + 64 + j], sh = sp[dblk + 64 + j];
        olo[j] = (__bf16)(ql * cl - qh * sl);
        ohi[j] = (__bf16)(qh * ch + ql * sh);
    }
    *(bf16x8*)(p + dblk)      = olo;
    *(bf16x8*)(p + dblk + 64) = ohi;
}

// V transpose via LDS tile: Vt[b][d][s] = KV[(b*S+s)*256 + 128 + d]
__global__ void vtrans(const __bf16* __restrict__ KV, __bf16* __restrict__ Vt) {
    __shared__ __bf16 T[128][72];
    const int tid = threadIdx.x;
    const int s0  = (blockIdx.x & (Sc / 64 - 1)) * 64;
    const int b   = blockIdx.x / (Sc / 64);
#pragma unroll
    for (int i = 0; i < 4; ++i) {
        int e = i * 256 + tid;          // 0..1023
        int s = e >> 4, dc = (e & 15) * 8;
        bf16x8 v = *(const bf16x8*)(KV + (long)(b * Sc + s0 + s) * 256 + 128 + dc);
#pragma unroll
        for (int j = 0; j < 8; ++j) T[dc + j][s] = v[j];
    }
    __syncthreads();
#pragma unroll
    for (int i = 0; i < 4; ++i) {
        int e = i * 256 + tid;
        int d = e >> 3, sc8 = (e & 7) * 8;
        bf16x8 v;
#pragma unroll
        for (int j = 0; j < 8; ++j) v[j] = T[d][sc8 + j];
        *(bf16x8*)(Vt + (long)(b * HDc + d) * Sc + s0 + sc8) = v;
    }
}

// ---------------------------------------------------------------------------
// Causal MQA flash attention v8: SINGLE-buffered Ks/Vs (41.9KB LDS -> 3
// blocks/CU, was 74.7KB -> 2) with a 4-barrier counted-vmcnt schedule (the
// gemm256 technique). Per-thread FIFO invariant at loop entry:
// outstanding = {K(kt) 4 ops, V(kt) 4 ops}.
//   WAITVM(4)  -> K(kt) landed (own ops); BARRIER -> all waves' K landed
//   QK(kt); BARRIER -> Ks free to overwrite
//   stage K(kt+1); softmax (covers V latency); WAITVM(4|0) -> V(kt) landed
//   BARRIER -> all waves' V landed; PV(kt); BARRIER -> Vs free
//   stage V(kt+1)   => invariant restored.
// ---------------------------------------------------------------------------
__global__ __launch_bounds__(256, 3)
void attn(const __bf16* __restrict__ Q,    // (B*S, H), RAW Wq output (no rope)
          const __bf16* __restrict__ KV,   // (B*S, 256): cols 0..127 = K (rope'd)
          const __bf16* __restrict__ Vt,   // (B, HD, S)
          const float* __restrict__ cosb,  // (S, HD)
          const float* __restrict__ sinb,  // (S, HD)
          __bf16* __restrict__ O) {        // (B*S, H)
    const int qt   = (gridDim.x - 1) - blockIdx.x;   // heavy blocks first
    const int bh   = blockIdx.y;
    const int b    = bh >> 5, h = bh & 31;
    const int tid  = threadIdx.x;
    const int wave = tid >> 6, lane = tid & 63;
    const int lrow = lane & 15, quad = lane >> 4;

    __shared__ __bf16 Ks[64][128];   // swizzled: phys col16 = logical ^ (row&15)
    __shared__ __bf16 Vs[128][64];   // swizzled: phys col16 = logical ^ (row&7)
    __shared__ __bf16 Ps[4][16][72];

    bf16x8 vone;
#pragma unroll
    for (int j = 0; j < 8; ++j) vone[j] = (__bf16)1.0f;

    const int q0 = qt * 128 + wave * 32;

    // staging address precompute
    const __bf16* kvb = KV + (long)b * Sc * 256;
    const __bf16* vtb = Vt + (long)b * HDc * Sc;
    int krow[4], kcol[4], vrow[4], vcol[4];
#pragma unroll
    for (int it = 0; it < 4; ++it) {
        int e = (wave * 4 + it) * 1024 + lane * 16;  // byte slot in 16KB tile
        int rk = e >> 8, cbk = (e >> 4) & 15;        // K: 256B rows
        krow[it] = rk; kcol[it] = ((cbk ^ (rk & 15)) * 8);
        int rv = e >> 7, cbv = (e >> 4) & 7;         // V: 128B rows
        vrow[it] = rv; vcol[it] = ((cbv ^ (rv & 7)) * 8);
    }

    auto stage_k = [&](int kt) {
#pragma unroll
        for (int it = 0; it < 4; ++it)
            gll16(kvb + (long)(kt * 64 + krow[it]) * 256 + kcol[it],
                  &Ks[0][0] + (wave * 4 + it) * 512, lane);
    };
    auto stage_v = [&](int kt) {
#pragma unroll
        for (int it = 0; it < 4; ++it)
            gll16(vtb + (long)vrow[it] * Sc + kt * 64 + vcol[it],
                  &Vs[0][0] + (wave * 4 + it) * 512, lane);
    };

    // issue tile-0 staging first; Q rope-load below hides its latency
    stage_k(0);
    stage_v(0);

    // Q-fragment load with fused RoPE + scale (1/sqrt(128) * log2e).
    const float qscale = 0.08838834764831845f * 1.4426950408889634f;
    bf16x8 aq[2][4];
#pragma unroll
    for (int qq = 0; qq < 2; ++qq) {
        const int s = q0 + qq * 16 + lrow;
        const __bf16* qp = Q + (long)(b * Sc + s) * Hc + h * HDc + quad * 8;
        const float* cp = cosb + s * HDc + quad * 8;
        const float* sp = sinb + s * HDc + quad * 8;
        bf16x8 raw[4];
#pragma unroll
        for (int c = 0; c < 4; ++c) raw[c] = *(const bf16x8*)(qp + c * 32);
#pragma unroll
        for (int c = 0; c < 2; ++c) {
#pragma unroll
            for (int j = 0; j < 8; ++j) {
                const int d = c * 32 + j;            // offset past quad*8 base
                float ql = (float)raw[c][j], qh = (float)raw[c + 2][j];
                float cl = cp[d],      sl = sp[d];
                float ch = cp[d + 64], sh = sp[d + 64];
                aq[qq][c][j]     = (__bf16)((ql * cl - qh * sl) * qscale);
                aq[qq][c + 2][j] = (__bf16)((qh * ch + ql * sh) * qscale);
            }
        }
    }

    f32x4 o[2][8] = {};
    f32x4 lac[2] = {};
    float mst[2][4];
#pragma unroll
    for (int qq = 0; qq < 2; ++qq)
#pragma unroll
        for (int r = 0; r < 4; ++r) mst[qq][r] = -3.0e38f;

    const int nt = 2 * qt + 2;

    for (int kt = 0; kt < nt; ++kt) {
        const bool more = (kt + 1 < nt);

        WAITVM(4);            // retire K(kt) (own 4 ops; V(kt) still in flight)
        BARRIER;              // all waves' K(kt) landed -> Ks readable

        // S = Q K^T, K-frags shared across both q halves
        f32x4 sc[2][4] = {};
        __builtin_amdgcn_s_setprio(1);
#pragma unroll
        for (int ct = 0; ct < 4; ++ct) {
#pragma unroll
            for (int c = 0; c < 4; ++c) {
                bf16x8 bk = *(const bf16x8*)&Ks[ct * 16 + lrow][(((c << 2) | quad) ^ lrow) << 3];
                sc[0][ct] = __builtin_amdgcn_mfma_f32_16x16x32_bf16(aq[0][c], bk, sc[0][ct], 0, 0, 0);
                sc[1][ct] = __builtin_amdgcn_mfma_f32_16x16x32_bf16(aq[1][c], bk, sc[1][ct], 0, 0, 0);
            }
        }
        __builtin_amdgcn_s_setprio(0);

        BARRIER;              // all waves done reading Ks -> safe to overwrite
        if (more) stage_k(kt + 1);   // outstanding: V(kt)[4], K(kt+1)[4]

        // softmax (VALU) overlaps K-issue and V-landing
        bf16x8 ap[2][2];
#pragma unroll
        for (int qq = 0; qq < 2; ++qq) {
            if (kt * 64 + 63 > q0 + qq * 16) {  // tile may cross the diagonal
#pragma unroll
                for (int ct = 0; ct < 4; ++ct) {
                    int kv = kt * 64 + ct * 16 + lrow;
#pragma unroll
                    for (int r = 0; r < 4; ++r) {
                        int qr = q0 + qq * 16 + quad * 4 + r;
                        if (kv > qr) sc[qq][ct][r] = -3.0e38f;
                    }
                }
            }

            // T13 defer-max (base-2 domain): full reduce+rescale only when a
            // row max grew past m_running + 8 (P bounded by 2^8).
            float lmax[4];
#pragma unroll
            for (int r = 0; r < 4; ++r)
                lmax[r] = fmaxf(fmaxf(sc[qq][0][r], sc[qq][1][r]),
                                fmaxf(sc[qq][2][r], sc[qq][3][r]));
            const bool near_ok = (lmax[0] <= mst[qq][0] + 8.0f) &&
                                 (lmax[1] <= mst[qq][1] + 8.0f) &&
                                 (lmax[2] <= mst[qq][2] + 8.0f) &&
                                 (lmax[3] <= mst[qq][3] + 8.0f);
            if (!__all(near_ok)) {
                float alf[4];
#pragma unroll
                for (int r = 0; r < 4; ++r) {
                    float mx = lmax[r];
#pragma unroll
                    for (int off = 1; off < 16; off <<= 1) mx = fmaxf(mx, __shfl_xor(mx, off, 64));
                    float mnew = fmaxf(mst[qq][r], mx);
                    alf[r]     = fast_exp2(mst[qq][r] - mnew);
                    mst[qq][r] = mnew;
                }
#pragma unroll
                for (int dt = 0; dt < 8; ++dt)
#pragma unroll
                    for (int r = 0; r < 4; ++r) o[qq][dt][r] *= alf[r];
#pragma unroll
                for (int r = 0; r < 4; ++r) lac[qq][r] *= alf[r];
            }
#pragma unroll
            for (int ct = 0; ct < 4; ++ct)
#pragma unroll
                for (int r = 0; r < 4; ++r)
                    sc[qq][ct][r] = fast_exp2(sc[qq][ct][r] - mst[qq][r]);

            // P -> LDS (C-layout -> A-layout), per-wave buffer (no barrier)
#pragma unroll
            for (int ct = 0; ct < 4; ++ct)
#pragma unroll
                for (int r = 0; r < 4; ++r)
                    Ps[wave][quad * 4 + r][ct * 16 + lrow] = (__bf16)sc[qq][ct][r];
#pragma unroll
            for (int ks = 0; ks < 2; ++ks)
                ap[qq][ks] = *(const bf16x8*)&Ps[wave][lrow][ks * 32 + quad * 8];
        }

        if (more) { WAITVM(4); } else { WAITVM(0); }  // retire V(kt)
        BARRIER;              // all waves' V(kt) landed -> Vs readable

        // O += P V  (V-frags shared across both q halves)
        __builtin_amdgcn_s_setprio(1);
#pragma unroll
        for (int dt = 0; dt < 8; ++dt) {
#pragma unroll
            for (int ks = 0; ks < 2; ++ks) {
                bf16x8 bv = *(const bf16x8*)&Vs[dt * 16 + lrow]
                                [(((ks << 2) | quad) ^ (lrow & 7)) << 3];
#pragma unroll
                for (int qq = 0; qq < 2; ++qq)
                    o[qq][dt] = __builtin_amdgcn_mfma_f32_16x16x32_bf16(ap[qq][ks], bv, o[qq][dt], 0, 0, 0);
            }
        }
        // l += P . ones  (ones B-frag is a constant splat — no LDS)
#pragma unroll
        for (int ks = 0; ks < 2; ++ks) {
#pragma unroll
            for (int qq = 0; qq < 2; ++qq)
                lac[qq] = __builtin_amdgcn_mfma_f32_16x16x32_bf16(ap[qq][ks], vone, lac[qq], 0, 0, 0);
        }
        __builtin_amdgcn_s_setprio(0);

        BARRIER;              // all waves done reading Vs -> safe to overwrite
        if (more) stage_v(kt + 1);   // outstanding: K(kt+1)[4], V(kt+1)[4]
    }

    // epilogue
#pragma unroll
    for (int qq = 0; qq < 2; ++qq)
#pragma unroll
        for (int r = 0; r < 4; ++r) {
            float inv = 1.f / lac[qq][r];
            int qr = q0 + qq * 16 + quad * 4 + r;
            __bf16* op = O + (long)(b * Sc + qr) * Hc + h * HDc;
#pragma unroll
            for (int dt = 0; dt < 8; ++dt) op[dt * 16 + lrow] = (__bf16)(o[qq][dt][r] * inv);
        }
}

// ---------------------------------------------------------------------------
extern "C" void kernel_launch(void* const* d_in, const int* in_sizes, int n_in,
                              void* d_out, int out_size, void* d_ws, size_t ws_size,
                              hipStream_t stream) {
    const float* hs   = (const float*)d_in[0];
    const float* cosb = (const float*)d_in[1];
    const float* sinb = (const float*)d_in[2];
    const float* Wq   = (const float*)d_in[3];
    const float* Wk   = (const float*)d_in[4];
    const float* Wv   = (const float*)d_in[5];
    const float* Wd   = (const float*)d_in[6];
    float* out = (float*)d_out;

    char* ws = (char*)d_ws;
    const long SZ_HS  = (long)Bc * Sc * Hc * 2;      // 32MB
    const long SZ_W   = (long)Hc * Hc * 2;           // 32MB
    const long SZ_KV  = (long)Bc * Sc * 256 * 2;     // 2MB
    __bf16* hs16  = (__bf16*)(ws);
    __bf16* wq16  = (__bf16*)(ws + SZ_HS);
    __bf16* wkv16 = (__bf16*)(ws + SZ_HS + SZ_W);
    __bf16* q16   = (__bf16*)(ws + SZ_HS + SZ_W + SZ_KV);
    __bf16* kv16  = (__bf16*)(ws + SZ_HS + SZ_W + SZ_KV + SZ_HS);
    __bf16* vt16  = (__bf16*)(ws + SZ_HS + SZ_W + SZ_KV + SZ_HS + SZ_KV);
    __bf16* att16 = hs16;   // reuse: hidden dead after Q/KV GEMMs
    __bf16* wd16  = wq16;   // reuse: Wq dead after Q GEMM

    const int nHS = Bc * Sc * Hc;   // 16M
    const int nW  = Hc * Hc;        // 16M

    cvt_f32_bf16<<<nHS / 1024, 256, 0, stream>>>(hs, hs16, nHS);
    cvt_f32_bf16<<<nW / 1024, 256, 0, stream>>>(Wq, wq16, nW);
    build_wkv<<<(256 * Hc) / 1024, 256, 0, stream>>>(Wk, Wv, wkv16);

    gemm256<__bf16><<<dim3(Hc / 256, (Bc * Sc) / 256), 512, 0, stream>>>(
        hs16, wq16, q16, Bc * Sc, Hc, Hc);
    gemm_bt64<__bf16><<<dim3(256 / 64, (Bc * Sc) / 64), 256, 0, stream>>>(
        hs16, wkv16, kv16, Bc * Sc, 256, Hc);

    cvt_f32_bf16<<<nW / 1024, 256, 0, stream>>>(Wd, wd16, nW);  // after Q GEMM

    rope_k<<<(Bc * Sc * 8) / 256, 256, 0, stream>>>(kv16, cosb, sinb);
    vtrans<<<Bc * (Sc / 64), 256, 0, stream>>>(kv16, vt16);

    attn<<<dim3(Sc / 128, Bc * NHc), 256, 0, stream>>>(q16, kv16, vt16, cosb, sinb, att16);

    gemm256<float><<<dim3(Hc / 256, (Bc * Sc) / 256), 512, 0, stream>>>(
        att16, wd16, out, Bc * Sc, Hc, Hc);
}

// Round 6
// 654.642 us; speedup vs baseline: 1.2678x; 1.2678x over previous
//
#include <hip/hip_runtime.h>
#include <hip/hip_bf16.h>
#include <math.h>

// Problem constants (reference: B,S,H,NH,HD = 2,2048,4096,32,128)
constexpr int Bc  = 2;
constexpr int Sc  = 2048;
constexpr int Hc  = 4096;
constexpr int NHc = 32;
constexpr int HDc = 128;

typedef __attribute__((ext_vector_type(8))) __bf16 bf16x8;
typedef __attribute__((ext_vector_type(4))) __bf16 bf16x4;
typedef __attribute__((ext_vector_type(4))) float  f32x4;

#if defined(__has_builtin)
#if __has_builtin(__builtin_amdgcn_global_load_lds)
#define HAS_GLL 1
#endif
#endif
#ifndef HAS_GLL
#define HAS_GLL 0
#endif

// raw v_exp_f32 (base-2). libm exp2f carries OCML edge handling; the builtin
// is a single instruction.
__device__ __forceinline__ float fast_exp2(float x) {
#if defined(__has_builtin)
#if __has_builtin(__builtin_amdgcn_exp2f)
    return __builtin_amdgcn_exp2f(x);
#else
    return exp2f(x);
#endif
#else
    return exp2f(x);
#endif
}

// compiler fence (no instructions) + raw barrier: syncthreads WITHOUT the
// vmcnt(0) drain.
#define CFENCE asm volatile("" ::: "memory")
#define BARRIER do { CFENCE; __builtin_amdgcn_s_barrier(); CFENCE; } while (0)
#define WAITVM(n) asm volatile("s_waitcnt vmcnt(" #n ")" ::: "memory")

// async global->LDS, 16B per lane. lds base must be wave-uniform; HW adds lane*16.
__device__ __forceinline__ void gll16(const __bf16* g, __bf16* lds_base, int lane) {
#if HAS_GLL
    __builtin_amdgcn_global_load_lds((const __attribute__((address_space(1))) void*)g,
                                     (__attribute__((address_space(3))) void*)lds_base,
                                     16, 0, 0);
#else
    *(int4*)(lds_base + lane * 8) = *(const int4*)g;
#endif
}

// ---------------------------------------------------------------------------
// fp32 -> bf16 conversion (kept for Wd, which must wait for Wq's buffer)
// ---------------------------------------------------------------------------
__global__ void cvt_f32_bf16(const float* __restrict__ in, __bf16* __restrict__ out, int n) {
    int i = (blockIdx.x * blockDim.x + threadIdx.x) * 4;
    if (i >= n) return;
    const float4 v = *(const float4*)(in + i);
    bf16x4 o;
    o[0] = (__bf16)v.x; o[1] = (__bf16)v.y; o[2] = (__bf16)v.z; o[3] = (__bf16)v.w;
    *(bf16x4*)(out + i) = o;
}

// ---------------------------------------------------------------------------
// Fused prep: cvt(hs) [blocks 0..16383] + cvt(Wq) [16384..32767] +
// build_wkv [32768..33791]. One dispatch instead of three (launch-gap tail).
// ---------------------------------------------------------------------------
__global__ void prep(const float* __restrict__ hs, const float* __restrict__ Wq,
                     const float* __restrict__ Wk, const float* __restrict__ Wv,
                     __bf16* __restrict__ hs16, __bf16* __restrict__ wq16,
                     __bf16* __restrict__ wkv16) {
    const int blk = blockIdx.x;
    if (blk < 16384) {
        int i = (blk * 256 + threadIdx.x) * 4;
        const float4 v = *(const float4*)(hs + i);
        bf16x4 o;
        o[0] = (__bf16)v.x; o[1] = (__bf16)v.y; o[2] = (__bf16)v.z; o[3] = (__bf16)v.w;
        *(bf16x4*)(hs16 + i) = o;
    } else if (blk < 32768) {
        int i = ((blk - 16384) * 256 + threadIdx.x) * 4;
        const float4 v = *(const float4*)(Wq + i);
        bf16x4 o;
        o[0] = (__bf16)v.x; o[1] = (__bf16)v.y; o[2] = (__bf16)v.z; o[3] = (__bf16)v.w;
        *(bf16x4*)(wq16 + i) = o;
    } else {
        int i = ((blk - 32768) * 256 + threadIdx.x) * 4;
        int row = i >> 12;
        int col = i & (Hc - 1);
        const float* src = (row < HDc) ? (Wk + (long)row * Hc + col)
                                       : (Wv + (long)(row - HDc) * Hc + col);
        const float4 v = *(const float4*)src;
        bf16x4 o;
        o[0] = (__bf16)v.x; o[1] = (__bf16)v.y; o[2] = (__bf16)v.z; o[3] = (__bf16)v.w;
        *(bf16x4*)(wkv16 + i) = o;
    }
}

// ---------------------------------------------------------------------------
// NT GEMM "gemm256": 256x256 tile, BK=64, 512 thr (8 waves, 2Mx4N of 128x64),
// 8-phase-per-2-K-tiles schedule with counted vmcnt. Measured: ~1.5 PF, correct.
// ---------------------------------------------------------------------------
template <typename OUT>
__global__ __launch_bounds__(512, 2)
void gemm256(const __bf16* __restrict__ A, const __bf16* __restrict__ B,
             OUT* __restrict__ C, int M, int N, int K) {
    __shared__ __bf16 As[2][256 * 64];
    __shared__ __bf16 Bs[2][256 * 64];

    const int tid  = threadIdx.x;
    const int wave = tid >> 6, lane = tid & 63;
    const int lrow = lane & 15, quad = lane >> 4;
    const int wm = wave >> 2, wn = wave & 3;

    // XCD-aware bijective chunked swizzle (nwg = 256, %8 == 0)
    const int nwg = gridDim.x * gridDim.y;
    const int bid = blockIdx.y * gridDim.x + blockIdx.x;
    const int wg  = (bid & 7) * (nwg >> 3) + (bid >> 3);
    const int m0  = (wg / gridDim.x) * 256;
    const int n0  = (wg % gridDim.x) * 256;

    f32x4 acc[8][4] = {};

    // staging precompute: 2 chunks (1KB = 8 rows) per thread per group,
    // chunk id c = wave*2+it. Source col inverse-swizzled so LDS is linear.
    int srow[4][2], sbase[4][2];
    const int rp   = lane >> 3;                 // row within 8-row chunk
    const int scol = ((lane & 7) ^ rp) << 3;    // logical elem col
#pragma unroll
    for (int it = 0; it < 2; ++it) {
        const int c   = wave * 2 + it;
        const int rb0 = (c < 8) ? c * 8 : 128 + (c - 8) * 8;  // A qi0: [0,64)+[128,192)
        const int rb1 = (c >> 2) * 64 + (c & 3) * 8;          // B qj0: 4x 32-row slabs
        srow[0][it] = rb0 + rp;       sbase[0][it] = rb0 * 64;
        srow[1][it] = rb1 + rp;       sbase[1][it] = rb1 * 64;
        srow[2][it] = rb1 + 32 + rp;  sbase[2][it] = (rb1 + 32) * 64;
        srow[3][it] = rb0 + 64 + rp;  sbase[3][it] = (rb0 + 64) * 64;
    }
    const __bf16* Ab = A + (long)m0 * K;
    const __bf16* Bb = B + (long)n0 * K;

    auto stageg = [&](int g, int bu, long k0) {
        const __bf16* gb = (g == 0 || g == 3) ? Ab : Bb;
        __bf16* lb = (g == 0 || g == 3) ? &As[bu][0] : &Bs[bu][0];
#pragma unroll
        for (int it = 0; it < 2; ++it)
            gll16(gb + (long)srow[g][it] * K + k0 + scol, lb + sbase[g][it], lane);
    };

    const int fc0  = ((quad ^ (lrow & 7)) << 3);        // phys col, k-half 0
    const int fc1  = (((4 | quad) ^ (lrow & 7)) << 3);  // phys col, k-half 1
    const int arow = wm * 128 + lrow;                   // + qi*64 + i2*16
    const int brow = wn * 64 + lrow;                    // + qj*32 + j2*16

    const int nk = K >> 6;
    // prologue: stage tile 0 -> buf 0
    stageg(0, 0, 0); stageg(1, 0, 0); stageg(2, 0, 0); stageg(3, 0, 0);
    WAITVM(4);
    BARRIER;

    for (int kt = 0; kt < nk; ++kt) {
        const int bu = kt & 1;
        const bool more = (kt + 1 < nk);
        const long k1 = (long)(kt + 1) * 64;
        bf16x8 af[2][4], bv0[2][2], bv1[2][2];

        // ---- phase 0: read af(qi=0)+bv0(qj=0); stage g0(kt+1); MFMA (0,0)
#pragma unroll
        for (int i2 = 0; i2 < 4; ++i2) {
            af[0][i2] = *(const bf16x8*)&As[bu][(arow + i2 * 16) * 64 + fc0];
            af[1][i2] = *(const bf16x8*)&As[bu][(arow + i2 * 16) * 64 + fc1];
        }
#pragma unroll
        for (int j2 = 0; j2 < 2; ++j2) {
            bv0[0][j2] = *(const bf16x8*)&Bs[bu][(brow + j2 * 16) * 64 + fc0];
            bv0[1][j2] = *(const bf16x8*)&Bs[bu][(brow + j2 * 16) * 64 + fc1];
        }
        if (more) { stageg(0, bu ^ 1, k1); WAITVM(4); } else { WAITVM(0); }
        BARRIER;
        __builtin_amdgcn_s_setprio(1);
#pragma unroll
        for (int c = 0; c < 2; ++c)
#pragma unroll
            for (int i2 = 0; i2 < 4; ++i2)
#pragma unroll
                for (int j2 = 0; j2 < 2; ++j2)
                    acc[i2][j2] = __builtin_amdgcn_mfma_f32_16x16x32_bf16(
                        af[c][i2], bv0[c][j2], acc[i2][j2], 0, 0, 0);
        __builtin_amdgcn_s_setprio(0);
        BARRIER;

        // ---- phase 1: read bv1(qj=1); stage g1(kt+1); MFMA (0,1)
#pragma unroll
        for (int j2 = 0; j2 < 2; ++j2) {
            bv1[0][j2] = *(const bf16x8*)&Bs[bu][(brow + 32 + j2 * 16) * 64 + fc0];
            bv1[1][j2] = *(const bf16x8*)&Bs[bu][(brow + 32 + j2 * 16) * 64 + fc1];
        }
        if (more) { stageg(1, bu ^ 1, k1); WAITVM(4); } else { WAITVM(0); }
        BARRIER;
        __builtin_amdgcn_s_setprio(1);
#pragma unroll
        for (int c = 0; c < 2; ++c)
#pragma unroll
            for (int i2 = 0; i2 < 4; ++i2)
#pragma unroll
                for (int j2 = 0; j2 < 2; ++j2)
                    acc[i2][2 + j2] = __builtin_amdgcn_mfma_f32_16x16x32_bf16(
                        af[c][i2], bv1[c][j2], acc[i2][2 + j2], 0, 0, 0);
        __builtin_amdgcn_s_setprio(0);
        BARRIER;

        // ---- phase 2: read af(qi=1); stage g2(kt+1); MFMA (1,0)
#pragma unroll
        for (int i2 = 0; i2 < 4; ++i2) {
            af[0][i2] = *(const bf16x8*)&As[bu][(arow + 64 + i2 * 16) * 64 + fc0];
            af[1][i2] = *(const bf16x8*)&As[bu][(arow + 64 + i2 * 16) * 64 + fc1];
        }
        if (more) { stageg(2, bu ^ 1, k1); WAITVM(4); } else { WAITVM(0); }
        BARRIER;
        __builtin_amdgcn_s_setprio(1);
#pragma unroll
        for (int c = 0; c < 2; ++c)
#pragma unroll
            for (int i2 = 0; i2 < 4; ++i2)
#pragma unroll
                for (int j2 = 0; j2 < 2; ++j2)
                    acc[4 + i2][j2] = __builtin_amdgcn_mfma_f32_16x16x32_bf16(
                        af[c][i2], bv0[c][j2], acc[4 + i2][j2], 0, 0, 0);
        __builtin_amdgcn_s_setprio(0);
        BARRIER;

        // ---- phase 3: no reads; stage g3(kt+1); MFMA (1,1)
        if (more) { stageg(3, bu ^ 1, k1); WAITVM(4); } else { WAITVM(0); }
        BARRIER;
        __builtin_amdgcn_s_setprio(1);
#pragma unroll
        for (int c = 0; c < 2; ++c)
#pragma unroll
            for (int i2 = 0; i2 < 4; ++i2)
#pragma unroll
                for (int j2 = 0; j2 < 2; ++j2)
                    acc[4 + i2][2 + j2] = __builtin_amdgcn_mfma_f32_16x16x32_bf16(
                        af[c][i2], bv1[c][j2], acc[4 + i2][2 + j2], 0, 0, 0);
        __builtin_amdgcn_s_setprio(0);
        BARRIER;
    }

#pragma unroll
    for (int i = 0; i < 8; ++i) {
        const int row = m0 + wm * 128 + i * 16 + quad * 4;
#pragma unroll
        for (int j = 0; j < 4; ++j) {
            const int col = n0 + wn * 64 + j * 16 + lrow;
            OUT* cp = C + (long)row * N + col;
#pragma unroll
            for (int r = 0; r < 4; ++r) cp[(long)r * N] = (OUT)acc[i][j][r];
        }
    }
}

// 64x64-tile KV GEMM, double-buffered.
template <typename OUT>
__global__ __launch_bounds__(256)
void gemm_bt64(const __bf16* __restrict__ A, const __bf16* __restrict__ B,
               OUT* __restrict__ C, int M, int N, int K) {
    __shared__ __bf16 As[2][64][64];
    __shared__ __bf16 Bs[2][64][64];

    const int tid  = threadIdx.x;
    const int wave = tid >> 6, lane = tid & 63;
    const int lrow = lane & 15, quad = lane >> 4;
    const int m0   = blockIdx.y * 64;
    const int n0   = blockIdx.x * 64;
    const int wr   = (wave >> 1) * 32;
    const int wc   = (wave & 1) * 32;

    f32x4 acc[2][2] = {};

    int srow[2], scol[2];
#pragma unroll
    for (int it = 0; it < 2; ++it) {
        int e = (wave * 2 + it) * 1024 + lane * 16;
        int r = e >> 7;
        int cb = (e >> 4) & 7;
        srow[it] = r;
        scol[it] = ((cb ^ (r & 7)) * 8);
    }
    const __bf16* Ab = A + (long)m0 * K;
    const __bf16* Bb = B + (long)n0 * K;

    auto stage = [&](int kt, int bu) {
        const long k0 = (long)kt * 64;
#pragma unroll
        for (int it = 0; it < 2; ++it)
            gll16(Ab + (long)srow[it] * K + k0 + scol[it], &As[bu][0][0] + (wave * 2 + it) * 512, lane);
#pragma unroll
        for (int it = 0; it < 2; ++it)
            gll16(Bb + (long)srow[it] * K + k0 + scol[it], &Bs[bu][0][0] + (wave * 2 + it) * 512, lane);
    };

    const int fcol0 = ((quad ^ (lrow & 7)) << 3);
    const int fcol1 = (((4 | quad) ^ (lrow & 7)) << 3);

    const int nk = K >> 6;
    stage(0, 0);
    for (int kt = 0; kt < nk; ++kt) {
        __syncthreads();                          // drains vmcnt -> tile kt ready
        if (kt + 1 < nk) stage(kt + 1, (kt + 1) & 1);
        const int bu = kt & 1;

#pragma unroll
        for (int c = 0; c < 2; ++c) {
            const int fc = c ? fcol1 : fcol0;
            bf16x8 af[2], bfv[2];
#pragma unroll
            for (int i = 0; i < 2; ++i) af[i]  = *(const bf16x8*)&As[bu][wr + i * 16 + lrow][fc];
#pragma unroll
            for (int j = 0; j < 2; ++j) bfv[j] = *(const bf16x8*)&Bs[bu][wc + j * 16 + lrow][fc];
#pragma unroll
            for (int i = 0; i < 2; ++i)
#pragma unroll
                for (int j = 0; j < 2; ++j)
                    acc[i][j] = __builtin_amdgcn_mfma_f32_16x16x32_bf16(af[i], bfv[j], acc[i][j], 0, 0, 0);
        }
    }

#pragma unroll
    for (int i = 0; i < 2; ++i) {
        const int row = m0 + wr + i * 16 + quad * 4;
#pragma unroll
        for (int j = 0; j < 2; ++j) {
            const int col = n0 + wc + j * 16 + lrow;
            OUT* cp = C + (long)row * N + col;
#pragma unroll
            for (int r = 0; r < 4; ++r) cp[(long)r * N] = (OUT)acc[i][j][r];
        }
    }
}

// ---------------------------------------------------------------------------
// Fused rope_k + vtrans: disjoint columns of KV (rope touches 0..127, vtrans
// reads 128..255) -> independent, one dispatch. Blocks 0..127 rope, 128..191
// transpose.
// ---------------------------------------------------------------------------
__global__ void ropek_vtrans(__bf16* __restrict__ KV, const float* __restrict__ cosb,
                             const float* __restrict__ sinb, __bf16* __restrict__ Vt) {
    __shared__ __bf16 T[128][72];
    const int tid = threadIdx.x;
    if (blockIdx.x < 128) {
        int gid  = blockIdx.x * 256 + tid;
        int row  = gid >> 3;
        int dblk = (gid & 7) * 8;
        int s    = row & (Sc - 1);
        __bf16* p = KV + (long)row * 256;
        const float* cp = cosb + s * HDc;
        const float* sp = sinb + s * HDc;
        bf16x8 lo = *(bf16x8*)(p + dblk);
        bf16x8 hi = *(bf16x8*)(p + dblk + 64);
        bf16x8 olo, ohi;
#pragma unroll
        for (int j = 0; j < 8; ++j) {
            float ql = (float)lo[j], qh = (float)hi[j];
            float cl = cp[dblk + j],      sl = sp[dblk + j];
            float ch = cp[dblk + 64 + j], sh = sp[dblk + 64 + j];
            olo[j] = (__bf16)(ql * cl - qh * sl);
            ohi[j] = (__bf16)(qh * ch + ql * sh);
        }
        *(bf16x8*)(p + dblk)      = olo;
        *(bf16x8*)(p + dblk + 64) = ohi;
    } else {
        const int vb = blockIdx.x - 128;
        const int s0 = (vb & (Sc / 64 - 1)) * 64;
        const int b  = vb / (Sc / 64);
#pragma unroll
        for (int i = 0; i < 4; ++i) {
            int e = i * 256 + tid;          // 0..1023
            int s = e >> 4, dc = (e & 15) * 8;
            bf16x8 v = *(const bf16x8*)(KV + (long)(b * Sc + s0 + s) * 256 + 128 + dc);
#pragma unroll
            for (int j = 0; j < 8; ++j) T[dc + j][s] = v[j];
        }
        __syncthreads();
#pragma unroll
        for (int i = 0; i < 4; ++i) {
            int e = i * 256 + tid;
            int d = e >> 3, sc8 = (e & 7) * 8;
            bf16x8 v;
#pragma unroll
            for (int j = 0; j < 8; ++j) v[j] = T[d][sc8 + j];
            *(bf16x8*)(Vt + (long)(b * HDc + d) * Sc + s0 + sc8) = v;
        }
    }
}

// ---------------------------------------------------------------------------
// Causal MQA flash attention (round-4 proven version, 189us): double-buffered
// async LDS staging, one __syncthreads per tile, fused RoPE-Q, T13 defer-max
// in base-2 via raw v_exp_f32, T5 setprio, vone splat.
// ---------------------------------------------------------------------------
__global__ __launch_bounds__(256, 2)
void attn(const __bf16* __restrict__ Q,    // (B*S, H), RAW Wq output (no rope)
          const __bf16* __restrict__ KV,   // (B*S, 256): cols 0..127 = K (rope'd)
          const __bf16* __restrict__ Vt,   // (B, HD, S)
          const float* __restrict__ cosb,  // (S, HD)
          const float* __restrict__ sinb,  // (S, HD)
          __bf16* __restrict__ O) {        // (B*S, H)
    const int qt   = (gridDim.x - 1) - blockIdx.x;   // heavy blocks first
    const int bh   = blockIdx.y;
    const int b    = bh >> 5, h = bh & 31;
    const int tid  = threadIdx.x;
    const int wave = tid >> 6, lane = tid & 63;
    const int lrow = lane & 15, quad = lane >> 4;

    __shared__ __bf16 Ks[2][64][128];   // swizzled: phys col16 = logical ^ (row&15)
    __shared__ __bf16 Vs[2][128][64];   // swizzled: phys col16 = logical ^ (row&7)
    __shared__ __bf16 Ps[4][16][72];

    bf16x8 vone;
#pragma unroll
    for (int j = 0; j < 8; ++j) vone[j] = (__bf16)1.0f;

    const int q0 = qt * 128 + wave * 32;

    // Q-fragment load with fused RoPE + scale (1/sqrt(128) * log2e).
    const float qscale = 0.08838834764831845f * 1.4426950408889634f;
    bf16x8 aq[2][4];
#pragma unroll
    for (int qq = 0; qq < 2; ++qq) {
        const int s = q0 + qq * 16 + lrow;
        const __bf16* qp = Q + (long)(b * Sc + s) * Hc + h * HDc + quad * 8;
        const float* cp = cosb + s * HDc + quad * 8;
        const float* sp = sinb + s * HDc + quad * 8;
        bf16x8 raw[4];
#pragma unroll
        for (int c = 0; c < 4; ++c) raw[c] = *(const bf16x8*)(qp + c * 32);
#pragma unroll
        for (int c = 0; c < 2; ++c) {
#pragma unroll
            for (int j = 0; j < 8; ++j) {
                const int d = c * 32 + j;            // offset past quad*8 base
                float ql = (float)raw[c][j], qh = (float)raw[c + 2][j];
                float cl = cp[d],      sl = sp[d];
                float ch = cp[d + 64], sh = sp[d + 64];
                aq[qq][c][j]     = (__bf16)((ql * cl - qh * sl) * qscale);
                aq[qq][c + 2][j] = (__bf16)((qh * ch + ql * sh) * qscale);
            }
        }
    }

    f32x4 o[2][8] = {};
    f32x4 lac[2] = {};
    float mst[2][4];
#pragma unroll
    for (int qq = 0; qq < 2; ++qq)
#pragma unroll
        for (int r = 0; r < 4; ++r) mst[qq][r] = -3.0e38f;

    // staging address precompute
    const __bf16* kvb = KV + (long)b * Sc * 256;
    const __bf16* vtb = Vt + (long)b * HDc * Sc;
    int krow[4], kcol[4], vrow[4], vcol[4];
#pragma unroll
    for (int it = 0; it < 4; ++it) {
        int e = (wave * 4 + it) * 1024 + lane * 16;  // byte slot in 16KB tile
        int rk = e >> 8, cbk = (e >> 4) & 15;        // K: 256B rows
        krow[it] = rk; kcol[it] = ((cbk ^ (rk & 15)) * 8);
        int rv = e >> 7, cbv = (e >> 4) & 7;         // V: 128B rows
        vrow[it] = rv; vcol[it] = ((cbv ^ (rv & 7)) * 8);
    }

    auto stage = [&](int kt, int bu) {
#pragma unroll
        for (int it = 0; it < 4; ++it) {
            gll16(kvb + (long)(kt * 64 + krow[it]) * 256 + kcol[it],
                  &Ks[bu][0][0] + (wave * 4 + it) * 512, lane);
            gll16(vtb + (long)vrow[it] * Sc + kt * 64 + vcol[it],
                  &Vs[bu][0][0] + (wave * 4 + it) * 512, lane);
        }
    };

    const int nt = 2 * qt + 2;
    stage(0, 0);

    for (int kt = 0; kt < nt; ++kt) {
        __syncthreads();                       // drains vmcnt -> tile kt ready
        if (kt + 1 < nt) stage(kt + 1, (kt + 1) & 1);   // async prefetch
        const int bu = kt & 1;

        // S = Q K^T, K-frags shared across both q halves
        f32x4 sc[2][4] = {};
        __builtin_amdgcn_s_setprio(1);
#pragma unroll
        for (int ct = 0; ct < 4; ++ct) {
#pragma unroll
            for (int c = 0; c < 4; ++c) {
                bf16x8 bk = *(const bf16x8*)&Ks[bu][ct * 16 + lrow][(((c << 2) | quad) ^ lrow) << 3];
                sc[0][ct] = __builtin_amdgcn_mfma_f32_16x16x32_bf16(aq[0][c], bk, sc[0][ct], 0, 0, 0);
                sc[1][ct] = __builtin_amdgcn_mfma_f32_16x16x32_bf16(aq[1][c], bk, sc[1][ct], 0, 0, 0);
            }
        }
        __builtin_amdgcn_s_setprio(0);

        bf16x8 ap[2][2];
#pragma unroll
        for (int qq = 0; qq < 2; ++qq) {
            if (kt * 64 + 63 > q0 + qq * 16) {  // tile may cross the diagonal
#pragma unroll
                for (int ct = 0; ct < 4; ++ct) {
                    int kv = kt * 64 + ct * 16 + lrow;
#pragma unroll
                    for (int r = 0; r < 4; ++r) {
                        int qr = q0 + qq * 16 + quad * 4 + r;
                        if (kv > qr) sc[qq][ct][r] = -3.0e38f;
                    }
                }
            }

            // T13 defer-max (base-2 domain): full reduce+rescale only when a
            // row max grew past m_running + 8 (P bounded by 2^8).
            float lmax[4];
#pragma unroll
            for (int r = 0; r < 4; ++r)
                lmax[r] = fmaxf(fmaxf(sc[qq][0][r], sc[qq][1][r]),
                                fmaxf(sc[qq][2][r], sc[qq][3][r]));
            const bool near_ok = (lmax[0] <= mst[qq][0] + 8.0f) &&
                                 (lmax[1] <= mst[qq][1] + 8.0f) &&
                                 (lmax[2] <= mst[qq][2] + 8.0f) &&
                                 (lmax[3] <= mst[qq][3] + 8.0f);
            if (!__all(near_ok)) {
                float alf[4];
#pragma unroll
                for (int r = 0; r < 4; ++r) {
                    float mx = lmax[r];
#pragma unroll
                    for (int off = 1; off < 16; off <<= 1) mx = fmaxf(mx, __shfl_xor(mx, off, 64));
                    float mnew = fmaxf(mst[qq][r], mx);
                    alf[r]     = fast_exp2(mst[qq][r] - mnew);
                    mst[qq][r] = mnew;
                }
#pragma unroll
                for (int dt = 0; dt < 8; ++dt)
#pragma unroll
                    for (int r = 0; r < 4; ++r) o[qq][dt][r] *= alf[r];
#pragma unroll
                for (int r = 0; r < 4; ++r) lac[qq][r] *= alf[r];
            }
#pragma unroll
            for (int ct = 0; ct < 4; ++ct)
#pragma unroll
                for (int r = 0; r < 4; ++r)
                    sc[qq][ct][r] = fast_exp2(sc[qq][ct][r] - mst[qq][r]);

            // P -> LDS (C-layout -> A-layout), per-wave buffer
#pragma unroll
            for (int ct = 0; ct < 4; ++ct)
#pragma unroll
                for (int r = 0; r < 4; ++r)
                    Ps[wave][quad * 4 + r][ct * 16 + lrow] = (__bf16)sc[qq][ct][r];
#pragma unroll
            for (int ks = 0; ks < 2; ++ks)
                ap[qq][ks] = *(const bf16x8*)&Ps[wave][lrow][ks * 32 + quad * 8];
        }

        // O += P V  (V-frags shared across both q halves)
        __builtin_amdgcn_s_setprio(1);
#pragma unroll
        for (int dt = 0; dt < 8; ++dt) {
#pragma unroll
            for (int ks = 0; ks < 2; ++ks) {
                bf16x8 bv = *(const bf16x8*)&Vs[bu][dt * 16 + lrow]
                                [(((ks << 2) | quad) ^ (lrow & 7)) << 3];
#pragma unroll
                for (int qq = 0; qq < 2; ++qq)
                    o[qq][dt] = __builtin_amdgcn_mfma_f32_16x16x32_bf16(ap[qq][ks], bv, o[qq][dt], 0, 0, 0);
            }
        }
        // l += P . ones  (ones B-frag is a constant splat — no LDS)
#pragma unroll
        for (int ks = 0; ks < 2; ++ks) {
#pragma unroll
            for (int qq = 0; qq < 2; ++qq)
                lac[qq] = __builtin_amdgcn_mfma_f32_16x16x32_bf16(ap[qq][ks], vone, lac[qq], 0, 0, 0);
        }
        __builtin_amdgcn_s_setprio(0);
    }

    // epilogue
#pragma unroll
    for (int qq = 0; qq < 2; ++qq)
#pragma unroll
        for (int r = 0; r < 4; ++r) {
            float inv = 1.f / lac[qq][r];
            int qr = q0 + qq * 16 + quad * 4 + r;
            __bf16* op = O + (long)(b * Sc + qr) * Hc + h * HDc;
#pragma unroll
            for (int dt = 0; dt < 8; ++dt) op[dt * 16 + lrow] = (__bf16)(o[qq][dt][r] * inv);
        }
}

// ---------------------------------------------------------------------------
extern "C" void kernel_launch(void* const* d_in, const int* in_sizes, int n_in,
                              void* d_out, int out_size, void* d_ws, size_t ws_size,
                              hipStream_t stream) {
    const float* hs   = (const float*)d_in[0];
    const float* cosb = (const float*)d_in[1];
    const float* sinb = (const float*)d_in[2];
    const float* Wq   = (const float*)d_in[3];
    const float* Wk   = (const float*)d_in[4];
    const float* Wv   = (const float*)d_in[5];
    const float* Wd   = (const float*)d_in[6];
    float* out = (float*)d_out;

    char* ws = (char*)d_ws;
    const long SZ_HS  = (long)Bc * Sc * Hc * 2;      // 32MB
    const long SZ_W   = (long)Hc * Hc * 2;           // 32MB
    const long SZ_KV  = (long)Bc * Sc * 256 * 2;     // 2MB
    __bf16* hs16  = (__bf16*)(ws);
    __bf16* wq16  = (__bf16*)(ws + SZ_HS);
    __bf16* wkv16 = (__bf16*)(ws + SZ_HS + SZ_W);
    __bf16* q16   = (__bf16*)(ws + SZ_HS + SZ_W + SZ_KV);
    __bf16* kv16  = (__bf16*)(ws + SZ_HS + SZ_W + SZ_KV + SZ_HS);
    __bf16* vt16  = (__bf16*)(ws + SZ_HS + SZ_W + SZ_KV + SZ_HS + SZ_KV);
    __bf16* att16 = hs16;   // reuse: hidden dead after Q/KV GEMMs
    __bf16* wd16  = wq16;   // reuse: Wq dead after Q GEMM

    const int nW  = Hc * Hc;        // 16M

    // fused cvt(hs) + cvt(Wq) + build_wkv (3 dispatches -> 1)
    prep<<<33792, 256, 0, stream>>>(hs, Wq, Wk, Wv, hs16, wq16, wkv16);

    gemm256<__bf16><<<dim3(Hc / 256, (Bc * Sc) / 256), 512, 0, stream>>>(
        hs16, wq16, q16, Bc * Sc, Hc, Hc);
    gemm_bt64<__bf16><<<dim3(256 / 64, (Bc * Sc) / 64), 256, 0, stream>>>(
        hs16, wkv16, kv16, Bc * Sc, 256, Hc);

    cvt_f32_bf16<<<nW / 1024, 256, 0, stream>>>(Wd, wd16, nW);  // after Q GEMM

    // fused rope_k + vtrans (2 dispatches -> 1; disjoint KV columns)
    ropek_vtrans<<<128 + Bc * (Sc / 64), 256, 0, stream>>>(kv16, cosb, sinb, vt16);

    attn<<<dim3(Sc / 128, Bc * NHc), 256, 0, stream>>>(q16, kv16, vt16, cosb, sinb, att16);

    gemm256<float><<<dim3(Hc / 256, (Bc * Sc) / 256), 512, 0, stream>>>(
        att16, wd16, out, Bc * Sc, Hc, Hc);
}